// Round 2
// baseline (583.607 us; speedup 1.0000x reference)
//
#include <hip/hip_runtime.h>

#define BATCH 4
#define CIN 64
#define HH 352
#define WW 1216
#define OCH 8
#define KK 3
#define OH (HH + 2)
#define OW (WW + 2)

#define TH 16       // tile height (pixels)
#define TW 64       // tile width (pixels)
#define PX 4        // pixels per thread (along W)
#define TXN 16      // threads along W
#define CCH 4       // channel chunk staged in LDS
#define HR (TH + 2) // halo rows = 18
#define HC (TW + 2) // halo cols = 66
#define HCP 68      // padded LDS row stride (floats)
#define NTHREADS 256

__global__ __launch_bounds__(NTHREADS, 2)
void cspn_kernel(const float* __restrict__ feature,
                 const float* __restrict__ conv_w,
                 const float* __restrict__ gamma,
                 const float* __restrict__ beta,
                 const float* __restrict__ mean,
                 const float* __restrict__ var,
                 float* __restrict__ out)
{
    __shared__ __align__(16) float sW[CIN * 9 * OCH];   // [c][tap][oc] = 4608 floats
    __shared__ __align__(16) float sF[CCH * HR * HCP];  // 4*18*68 = 4896 floats

    const int tid = threadIdx.x;
    const int b   = blockIdx.z;
    const int h0  = blockIdx.y * TH;
    const int w0  = blockIdx.x * TW;
    const int tx  = tid & (TXN - 1);
    const int ty  = tid >> 4;

    // Repack weights into LDS: sW[(c*9+tap)*8 + oc] = conv_w[oc][c][tap]
    for (int i = tid; i < CIN * 9 * OCH; i += NTHREADS) {
        int ct = i >> 3;   // c*9 + tap
        int oc = i & 7;
        sW[i] = conv_w[oc * (CIN * 9) + ct];
    }

    float acc[PX][OCH];
#pragma unroll
    for (int p = 0; p < PX; ++p)
#pragma unroll
        for (int o = 0; o < OCH; ++o) acc[p][o] = 0.f;

    const float* fb = feature + (size_t)b * CIN * HH * WW;

    for (int c0 = 0; c0 < CIN; c0 += CCH) {
        __syncthreads();
        // Stage CCH channels of the halo tile
        for (int i = tid; i < CCH * HR * HC; i += NTHREADS) {
            int ch  = i / (HR * HC);
            int rem = i - ch * (HR * HC);
            int r   = rem / HC;
            int col = rem - r * HC;
            int gh = h0 - 1 + r;
            int gw = w0 - 1 + col;
            float v = 0.f;
            if ((unsigned)gh < (unsigned)HH && (unsigned)gw < (unsigned)WW)
                v = fb[((size_t)(c0 + ch) * HH + gh) * WW + gw];
            sF[(ch * HR + r) * HCP + col] = v;
        }
        __syncthreads();

#pragma unroll
        for (int ch = 0; ch < CCH; ++ch) {
            // 3 rows x 6 cols of staged feature for this thread's 1x4 strip
            float f[3][6];
#pragma unroll
            for (int r = 0; r < 3; ++r) {
                const float* base = &sF[(ch * HR + ty + r) * HCP + tx * PX];
                float4 a  = *(const float4*)base;
                float2 bb = *(const float2*)(base + 4);
                f[r][0] = a.x; f[r][1] = a.y; f[r][2] = a.z; f[r][3] = a.w;
                f[r][4] = bb.x; f[r][5] = bb.y;
            }
            const float* wbase = &sW[(size_t)(c0 + ch) * 9 * OCH];
#pragma unroll
            for (int tap = 0; tap < 9; ++tap) {
                const int dh = tap / 3, dw = tap % 3;
                float4 wa = *(const float4*)(wbase + tap * OCH);
                float4 wb = *(const float4*)(wbase + tap * OCH + 4);
                float wv[OCH] = {wa.x, wa.y, wa.z, wa.w, wb.x, wb.y, wb.z, wb.w};
#pragma unroll
                for (int p = 0; p < PX; ++p) {
                    const float fv = f[dh][p + dw];
#pragma unroll
                    for (int o = 0; o < OCH; ++o)
                        acc[p][o] = fmaf(fv, wv[o], acc[p][o]);
                }
            }
        }
    }

    // BN params (uniform scalar loads)
    float scl[OCH], mn[OCH], bt[OCH];
#pragma unroll
    for (int o = 0; o < OCH; ++o) {
        scl[o] = gamma[o] * rsqrtf(var[o] + 1e-5f);
        mn[o]  = mean[o];
        bt[o]  = beta[o];
    }

    const int h    = h0 + ty;
    const int wcol = w0 + tx * PX;
    float* ob = out + (size_t)b * 9 * OH * OW;

    float g[PX][OCH];
    float midv[PX];
#pragma unroll
    for (int p = 0; p < PX; ++p) {
        float asum = 0.f;
#pragma unroll
        for (int o = 0; o < OCH; ++o) {
            float v = (acc[p][o] - mn[o]) * scl[o] + bt[o];
            g[p][o] = v;
            asum += fabsf(v);
        }
        float inv = 1.f / asum;
        float ssum = 0.f;
#pragma unroll
        for (int o = 0; o < OCH; ++o) { g[p][o] *= inv; ssum += g[p][o]; }
        midv[p] = 1.f - ssum;
    }

    // Scatter 9 shifted planes: out[b][t][h+i][w+j] = ch_t[h][w]
#pragma unroll
    for (int t = 0; t < 9; ++t) {
        const int i = t / 3, j = t % 3;
        float* row = ob + ((size_t)t * OH + (h + i)) * OW + (wcol + j);
#pragma unroll
        for (int p = 0; p < PX; ++p) {
            float v = (t < 4) ? g[p][t] : ((t == 4) ? midv[p] : g[p][t - 1]);
            row[p] = v;
        }
    }
}

extern "C" void kernel_launch(void* const* d_in, const int* in_sizes, int n_in,
                              void* d_out, int out_size, void* d_ws, size_t ws_size,
                              hipStream_t stream) {
    const float* feature = (const float*)d_in[0];
    const float* conv_w  = (const float*)d_in[1];
    const float* gamma   = (const float*)d_in[2];
    const float* beta    = (const float*)d_in[3];
    const float* mean    = (const float*)d_in[4];
    const float* var     = (const float*)d_in[5];
    float* out = (float*)d_out;

    // Zero output (covers the pad borders); graph-capturable.
    hipMemsetAsync(out, 0, (size_t)out_size * sizeof(float), stream);

    dim3 grid(WW / TW, HH / TH, BATCH);  // 19 x 22 x 4
    dim3 block(NTHREADS);
    cspn_kernel<<<grid, block, 0, stream>>>(feature, conv_w, gamma, beta, mean, var, out);
}

// Round 3
// 444.459 us; speedup vs baseline: 1.3131x; 1.3131x over previous
//
#include <hip/hip_runtime.h>

#define BATCH 4
#define CIN 64
#define HH 352
#define WW 1216
#define OCH 8
#define OHH 354
#define OWW 1218
#define HW (HH * WW)

#define PX 4        // cols per thread
#define TY 2        // rows per thread
#define TILE_W 64   // 16 tx * 4
#define TILE_H 32   // 16 ty * 2

// Repack weights with BN folded in: w2[c*72 + tap*8 + oc] = conv_w[oc][c][tap] * scl[oc]
// bias at w2[4608 + oc] = beta - mean*scl
__global__ void repack_kernel(const float* __restrict__ conv_w,
                              const float* __restrict__ gamma,
                              const float* __restrict__ beta,
                              const float* __restrict__ mean,
                              const float* __restrict__ var,
                              float* __restrict__ w2)
{
    int tid = blockIdx.x * 256 + threadIdx.x;
    if (tid < CIN * 9 * OCH) {
        int ct = tid >> 3;   // c*9 + tap
        int oc = tid & 7;
        float scl = gamma[oc] * rsqrtf(var[oc] + 1e-5f);
        w2[tid] = conv_w[oc * (CIN * 9) + ct] * scl;
    }
    if (tid < OCH) {
        float scl = gamma[tid] * rsqrtf(var[tid] + 1e-5f);
        w2[CIN * 9 * OCH + tid] = beta[tid] - mean[tid] * scl;
    }
}

__global__ __launch_bounds__(256, 4)
void conv_kernel(const float* __restrict__ feature,
                 const float* __restrict__ w2all,
                 float* __restrict__ out)
{
    const int tid = threadIdx.x;
    const int tx = tid & 15, ty = tid >> 4;
    const int b  = blockIdx.z;
    const int h0 = blockIdx.y * TILE_H + ty * TY;  // first output row of this thread
    const int w0 = blockIdx.x * TILE_W + tx * PX;  // first output col of this thread

    // Channel-invariant per-thread load offsets (elements) + 0/1 edge masks.
    // Per feature row rr (gh = h0-1+rr): three aligned float4 loads at
    // cols {w0-4, w0, w0+4} (clamped); used elements: a.w (col w0-1),
    // m.xyzw (w0..w0+3), e.x (col w0+4).
    int voff[4][3];
    float rowm[4], cm0[4], cm5[4];
    const bool c0ok = (w0 - 1) >= 0;
    const bool c5ok = (w0 + 4) < WW;
    const int cl1 = max(w0 - 4, 0);
    const int cl3 = min(w0 + 4, WW - 4);
#pragma unroll
    for (int rr = 0; rr < 4; ++rr) {
        int gh = h0 - 1 + rr;
        bool rok = (unsigned)gh < (unsigned)HH;
        int sgh = min(max(gh, 0), HH - 1);
        int rb = sgh * WW;
        voff[rr][0] = rb + cl1;
        voff[rr][1] = rb + w0;
        voff[rr][2] = rb + cl3;
        rowm[rr] = rok ? 1.f : 0.f;
        cm0[rr]  = (rok & c0ok) ? 1.f : 0.f;
        cm5[rr]  = (rok & c5ok) ? 1.f : 0.f;
    }

    float acc[TY][PX][OCH];
#pragma unroll
    for (int oy = 0; oy < TY; ++oy)
#pragma unroll
        for (int p = 0; p < PX; ++p)
#pragma unroll
            for (int o = 0; o < OCH; ++o) acc[oy][p][o] = 0.f;

    const float* fb = feature + (size_t)b * CIN * HW;

    for (int c = 0; c < CIN; ++c) {
        const float* cb = fb + c * HW;
        float f[4][6];
#pragma unroll
        for (int rr = 0; rr < 4; ++rr) {
            float4 a = *(const float4*)(cb + voff[rr][0]);
            float4 m = *(const float4*)(cb + voff[rr][1]);
            float4 e = *(const float4*)(cb + voff[rr][2]);
            f[rr][0] = a.w * cm0[rr];
            f[rr][1] = m.x * rowm[rr];
            f[rr][2] = m.y * rowm[rr];
            f[rr][3] = m.z * rowm[rr];
            f[rr][4] = m.w * rowm[rr];
            f[rr][5] = e.x * cm5[rr];
        }
        // Weights: block-uniform indices -> s_load; v_fmac_f32 v,s,v
        const float* wc = w2all + c * 72;
#pragma unroll
        for (int dh = 0; dh < 3; ++dh)
#pragma unroll
            for (int dw = 0; dw < 3; ++dw)
#pragma unroll
                for (int o = 0; o < OCH; ++o) {
                    float w = wc[(dh * 3 + dw) * OCH + o];
#pragma unroll
                    for (int oy = 0; oy < TY; ++oy)
#pragma unroll
                        for (int p = 0; p < PX; ++p)
                            acc[oy][p][o] = fmaf(f[oy + dh][p + dw], w, acc[oy][p][o]);
                }
    }

    // Epilogue: bias, L1-normalize across 8 channels, mid = 1 - sum, scatter 9 planes.
    const float* bb = w2all + CIN * 9 * OCH;
    float sb[OCH];
#pragma unroll
    for (int o = 0; o < OCH; ++o) sb[o] = bb[o];

    float* ob = out + (size_t)b * 9 * OHH * OWW;
#pragma unroll
    for (int oy = 0; oy < TY; ++oy) {
        const int h = h0 + oy;
#pragma unroll
        for (int p = 0; p < PX; ++p) {
            const int w = w0 + p;
            float g[OCH];
            float asum = 0.f;
#pragma unroll
            for (int o = 0; o < OCH; ++o) {
                float v = acc[oy][p][o] + sb[o];
                g[o] = v;
                asum += fabsf(v);
            }
            float inv = 1.0f / asum;
            float ss = 0.f;
#pragma unroll
            for (int o = 0; o < OCH; ++o) { g[o] *= inv; ss += g[o]; }
            float mid = 1.0f - ss;
#pragma unroll
            for (int t = 0; t < 9; ++t) {
                int i = t / 3, j = t - i * 3;
                float v = (t < 4) ? g[t] : ((t == 4) ? mid : g[t - 1]);
                ob[((size_t)t * OHH + (h + i)) * OWW + (w + j)] = v;
            }
        }
    }
}

extern "C" void kernel_launch(void* const* d_in, const int* in_sizes, int n_in,
                              void* d_out, int out_size, void* d_ws, size_t ws_size,
                              hipStream_t stream) {
    const float* feature = (const float*)d_in[0];
    const float* conv_w  = (const float*)d_in[1];
    const float* gamma   = (const float*)d_in[2];
    const float* beta    = (const float*)d_in[3];
    const float* mean    = (const float*)d_in[4];
    const float* var     = (const float*)d_in[5];
    float* out = (float*)d_out;
    float* w2  = (float*)d_ws;   // 4608 + 8 floats

    // Zero output (pad borders). Graph-capturable.
    hipMemsetAsync(out, 0, (size_t)out_size * sizeof(float), stream);

    repack_kernel<<<(CIN * 9 * OCH + 255) / 256, 256, 0, stream>>>(
        conv_w, gamma, beta, mean, var, w2);

    dim3 grid(WW / TILE_W, HH / TILE_H, BATCH);  // 19 x 11 x 4
    conv_kernel<<<grid, 256, 0, stream>>>(feature, w2, out);
}

// Round 4
// 267.703 us; speedup vs baseline: 2.1801x; 1.6603x over previous
//
#include <hip/hip_runtime.h>

#define BATCH 4
#define CIN 64
#define HH 352
#define WW 1216
#define OCH 8
#define OHH 354
#define OWW 1218
#define HW (HH * WW)

#define PX 4        // cols per thread
#define TY 2        // rows per thread
#define TILE_W 64   // 16 tx * 4
#define TILE_H 32   // 16 ty * 2

// Repack weights with BN folded in: w2[c*72 + tap*8 + oc] = conv_w[oc][c][tap] * scl[oc]
// bias at w2[4608 + oc] = beta - mean*scl
__global__ void repack_kernel(const float* __restrict__ conv_w,
                              const float* __restrict__ gamma,
                              const float* __restrict__ beta,
                              const float* __restrict__ mean,
                              const float* __restrict__ var,
                              float* __restrict__ w2)
{
    int tid = blockIdx.x * 256 + threadIdx.x;
    if (tid < CIN * 9 * OCH) {
        int ct = tid >> 3;   // c*9 + tap
        int oc = tid & 7;
        float scl = gamma[oc] * rsqrtf(var[oc] + 1e-5f);
        w2[tid] = conv_w[oc * (CIN * 9) + ct] * scl;
    }
    if (tid < OCH) {
        float scl = gamma[tid] * rsqrtf(var[tid] + 1e-5f);
        w2[CIN * 9 * OCH + tid] = beta[tid] - mean[tid] * scl;
    }
}

__global__ __launch_bounds__(256, 2)   // was (256,4): forced VGPR cap 64 -> ~50 regs spilled to scratch
void conv_kernel(const float* __restrict__ feature,
                 const float* __restrict__ w2all,
                 float* __restrict__ out)
{
    const int tid = threadIdx.x;
    const int tx = tid & 15, ty = tid >> 4;
    const int b  = blockIdx.z;
    const int h0 = blockIdx.y * TILE_H + ty * TY;  // first output row of this thread
    const int w0 = blockIdx.x * TILE_W + tx * PX;  // first output col of this thread

    // Channel-invariant per-thread load offsets (elements) + 0/1 edge masks.
    // Per feature row rr (gh = h0-1+rr): three aligned float4 loads at
    // cols {w0-4, w0, w0+4} (clamped); used elements: a.w (col w0-1),
    // m.xyzw (w0..w0+3), e.x (col w0+4).
    int voff[4][3];
    float rowm[4], cm0[4], cm5[4];
    const bool c0ok = (w0 - 1) >= 0;
    const bool c5ok = (w0 + 4) < WW;
    const int cl1 = max(w0 - 4, 0);
    const int cl3 = min(w0 + 4, WW - 4);
#pragma unroll
    for (int rr = 0; rr < 4; ++rr) {
        int gh = h0 - 1 + rr;
        bool rok = (unsigned)gh < (unsigned)HH;
        int sgh = min(max(gh, 0), HH - 1);
        int rb = sgh * WW;
        voff[rr][0] = rb + cl1;
        voff[rr][1] = rb + w0;
        voff[rr][2] = rb + cl3;
        rowm[rr] = rok ? 1.f : 0.f;
        cm0[rr]  = (rok & c0ok) ? 1.f : 0.f;
        cm5[rr]  = (rok & c5ok) ? 1.f : 0.f;
    }

    float acc[TY][PX][OCH];
#pragma unroll
    for (int oy = 0; oy < TY; ++oy)
#pragma unroll
        for (int p = 0; p < PX; ++p)
#pragma unroll
            for (int o = 0; o < OCH; ++o) acc[oy][p][o] = 0.f;

    const float* fb = feature + (size_t)b * CIN * HW;

    for (int c = 0; c < CIN; ++c) {
        const float* cb = fb + c * HW;
        float f[4][6];
#pragma unroll
        for (int rr = 0; rr < 4; ++rr) {
            float4 a = *(const float4*)(cb + voff[rr][0]);
            float4 m = *(const float4*)(cb + voff[rr][1]);
            float4 e = *(const float4*)(cb + voff[rr][2]);
            f[rr][0] = a.w * cm0[rr];
            f[rr][1] = m.x * rowm[rr];
            f[rr][2] = m.y * rowm[rr];
            f[rr][3] = m.z * rowm[rr];
            f[rr][4] = m.w * rowm[rr];
            f[rr][5] = e.x * cm5[rr];
        }
        // Weights: block-uniform indices -> s_load; v_fmac_f32 v,s,v
        const float* wc = w2all + c * 72;
#pragma unroll
        for (int dh = 0; dh < 3; ++dh)
#pragma unroll
            for (int dw = 0; dw < 3; ++dw)
#pragma unroll
                for (int o = 0; o < OCH; ++o) {
                    float w = wc[(dh * 3 + dw) * OCH + o];
#pragma unroll
                    for (int oy = 0; oy < TY; ++oy)
#pragma unroll
                        for (int p = 0; p < PX; ++p)
                            acc[oy][p][o] = fmaf(f[oy + dh][p + dw], w, acc[oy][p][o]);
                }
    }

    // Epilogue: bias, L1-normalize across 8 channels, mid = 1 - sum, scatter 9 planes.
    const float* bb = w2all + CIN * 9 * OCH;
    float sb[OCH];
#pragma unroll
    for (int o = 0; o < OCH; ++o) sb[o] = bb[o];

    float* ob = out + (size_t)b * 9 * OHH * OWW;
#pragma unroll
    for (int oy = 0; oy < TY; ++oy) {
        const int h = h0 + oy;
#pragma unroll
        for (int p = 0; p < PX; ++p) {
            const int w = w0 + p;
            float g[OCH];
            float asum = 0.f;
#pragma unroll
            for (int o = 0; o < OCH; ++o) {
                float v = acc[oy][p][o] + sb[o];
                g[o] = v;
                asum += fabsf(v);
            }
            float inv = 1.0f / asum;
            float ss = 0.f;
#pragma unroll
            for (int o = 0; o < OCH; ++o) { g[o] *= inv; ss += g[o]; }
            float mid = 1.0f - ss;
#pragma unroll
            for (int t = 0; t < 9; ++t) {
                int i = t / 3, j = t - i * 3;
                float v = (t < 4) ? g[t] : ((t == 4) ? mid : g[t - 1]);
                ob[((size_t)t * OHH + (h + i)) * OWW + (w + j)] = v;
            }
        }
    }
}

extern "C" void kernel_launch(void* const* d_in, const int* in_sizes, int n_in,
                              void* d_out, int out_size, void* d_ws, size_t ws_size,
                              hipStream_t stream) {
    const float* feature = (const float*)d_in[0];
    const float* conv_w  = (const float*)d_in[1];
    const float* gamma   = (const float*)d_in[2];
    const float* beta    = (const float*)d_in[3];
    const float* mean    = (const float*)d_in[4];
    const float* var     = (const float*)d_in[5];
    float* out = (float*)d_out;
    float* w2  = (float*)d_ws;   // 4608 + 8 floats

    // Zero output (pad borders). Graph-capturable.
    hipMemsetAsync(out, 0, (size_t)out_size * sizeof(float), stream);

    repack_kernel<<<(CIN * 9 * OCH + 255) / 256, 256, 0, stream>>>(
        conv_w, gamma, beta, mean, var, w2);

    dim3 grid(WW / TILE_W, HH / TILE_H, BATCH);  // 19 x 11 x 4
    conv_kernel<<<grid, 256, 0, stream>>>(feature, w2, out);
}